// Round 12
// baseline (199.341 us; speedup 1.0000x reference)
//
#include <hip/hip_runtime.h>

#define LOG2E 1.4426950408889634f

typedef _Float16 f16x8_t __attribute__((ext_vector_type(8)));
typedef _Float16 f16x4_t __attribute__((ext_vector_type(4)));
typedef _Float16 f16x2_t __attribute__((ext_vector_type(2)));
typedef float    f32x4_t __attribute__((ext_vector_type(4)));

#define MFMA32(a, b, c) __builtin_amdgcn_mfma_f32_16x16x32_f16(a, b, c, 0, 0, 0)
#define MFMA16(a, b, c) __builtin_amdgcn_mfma_f32_16x16x16f16(a, b, c, 0, 0, 0)

// async 16B/lane global->LDS copy. LDS dest is wave-uniform base + lane*16.
__device__ __forceinline__ void async_copy16(void* lds, const void* g) {
    __builtin_amdgcn_global_load_lds(
        (const __attribute__((address_space(1))) unsigned char*)g,
        (__attribute__((address_space(3))) unsigned char*)lds, 16, 0, 0);
}

// ---------------- fused prep: cast x->fp16 + transpose-cast both weight mats ----------
// blockIdx.x ranges: [0,4096) cast, [4096,4864) w_qkv 64x64 tiles, [4864,5120) w_proj.
__global__ void prep_k(const float* __restrict__ x, _Float16* __restrict__ xh,
                       const float* __restrict__ wq, _Float16* __restrict__ wqT,
                       const float* __restrict__ wp, _Float16* __restrict__ wpT) {
    __shared__ _Float16 tl[64][65];
    const int bx = blockIdx.x, t = threadIdx.x;
    if (bx < 4096) {
        const int i = bx * 256 + t;
        float4 v = ((const float4*)x)[i];
        f16x4_t o = { (_Float16)v.x, (_Float16)v.y, (_Float16)v.z, (_Float16)v.w };
        ((f16x4_t*)xh)[i] = o;
        return;
    }
    const float* in; _Float16* out; int C, bxx, byy;
    if (bx < 4864) { const int id = bx - 4096; in = wq; out = wqT; C = 3072; bxx = id % 48; byy = id / 48; }
    else           { const int id = bx - 4864; in = wp; out = wpT; C = 1024; bxx = id % 16; byy = id / 16; }
    const int R = 1024;
    const int c = t & 63;
    const int r4 = t >> 6;
    const int r0 = byy * 64, c0 = bxx * 64;
#pragma unroll
    for (int i = 0; i < 16; ++i) {
        int r = r4 + i * 4;
        tl[c][r] = (_Float16)in[(size_t)(r0 + r) * C + c0 + c];
    }
    __syncthreads();
#pragma unroll
    for (int i = 0; i < 16; ++i) {
        int rr = r4 + i * 4;
        out[(size_t)(c0 + rr) * R + r0 + c] = tl[rr][c];
    }
}

// ---------------- GEMM: C[M][N] = A[M][K] * BT[N][K]^T (+bias), fp16 in ----------------
// NEW (T3 2-phase): BK=64 DOUBLE-buffered K-loop — stage tile t+1 BEFORE computing
// tile t; ONE barrier per step (the attn-proven pattern). The load latency that the
// old zero-phase loop (issue -> vmcnt(0) drain -> compute) exposed every step now
// hides under the 32-MFMA compute window. LDS 64KB -> 2 blocks/CU (capacity-neutral
// to first order for a throughput-bound kernel; the overlap is the net gain).
// LNQK epilogues (QKV projection) unchanged:
//  - Q/K thirds (n0<2048): fused per-head LayerNorm; wave's acc = 64 tokens x one head.
//  - V third (n0>=2048): emit pre-baked VTg MFMA tiles DIRECTLY (fused vtrans).
template <typename OutT, bool BIAS, bool LNQK>
__global__ __launch_bounds__(256, 2)
void gemm_f16_k(const _Float16* __restrict__ A, const _Float16* __restrict__ BT,
                OutT* __restrict__ C, const float* __restrict__ bias,
                _Float16* __restrict__ VTg,
                const float* __restrict__ ln_w, const float* __restrict__ ln_b,
                int M, int N, int K) {
    __shared__ _Float16 As[2][2][128][32];   // [buf][s-plane][row][kk] 32KB
    __shared__ _Float16 Bs[2][2][128][32];   // 32KB
    const int tid = threadIdx.x;
    const int wid = tid >> 6, lane = tid & 63;
    const int qd = lane >> 4, ln = lane & 15;
    const int m0 = blockIdx.x * 128, n0 = blockIdx.y * 128;
    const int wm = (wid >> 1) * 64, wn = (wid & 1) * 64;

    f32x4_t acc[4][4] = {};

    const int srow = lane >> 2;
    const int skk  = (lane & 3) * 8;

    auto stage = [&](int buf, int k0) {      // 8 async_copy16 per wave
#pragma unroll
        for (int p = 0; p < 4; ++p) {
            const int seg = p * 4 + wid;           // 0..15
            const int s   = seg >> 3;
            const int rg  = seg & 7;
            const int row = rg * 16 + srow;
            const size_t goff = (size_t)row * K + k0 + s * 32 + skk;
            async_copy16(&As[buf][0][0][0] + seg * 512, A  + (size_t)m0 * K + goff);
            async_copy16(&Bs[buf][0][0][0] + seg * 512, BT + (size_t)n0 * K + goff);
        }
    };

    stage(0, 0);
    for (int k0 = 0; k0 < K; k0 += 64) {
        const int buf = (k0 >> 6) & 1;
        // barrier: (a) this wave's loads for buf (issued last iter) drained via the
        // implicit vmcnt(0); (b) joins all waves -> buf fully staged, buf^1 fully
        // consumed by the compute that preceded this barrier in program order.
        __syncthreads();
        if (k0 + 64 < K) stage(buf ^ 1, k0 + 64);
#pragma unroll
        for (int s = 0; s < 2; ++s) {
            f16x8_t a[4], b[4];
#pragma unroll
            for (int i = 0; i < 4; ++i)
                a[i] = *(const f16x8_t*)&As[buf][s][wm + i * 16 + ln][qd * 8];
#pragma unroll
            for (int j = 0; j < 4; ++j)
                b[j] = *(const f16x8_t*)&Bs[buf][s][wn + j * 16 + ln][qd * 8];
#pragma unroll
            for (int i = 0; i < 4; ++i)
#pragma unroll
                for (int j = 0; j < 4; ++j)
                    acc[i][j] = MFMA32(a[i], b[j], acc[i][j]);
        }
    }

    if constexpr (LNQK) {
        if (n0 >= 2048) {                           // V third -> VTg (vtrans fused)
            __syncthreads();                        // safe to reuse As as scratch
            const int h2  = ((n0 - 2048) >> 6) + (wn >> 6);
            const int row0 = m0 + wm;               // 64-token aligned
            const int bb  = row0 >> 11;
            const int tt  = (row0 & 2047) >> 6;
            const size_t obase = ((size_t)(bb * 16 + h2)) * 131072 + (size_t)tt * 4096;
            _Float16* tlw = &As[0][0][0][0] + wid * 1088;   // 16 rows x 68 halfs per wave
#pragma unroll
            for (int j = 0; j < 4; ++j) {           // d-group j*16 .. j*16+15
#pragma unroll
                for (int i = 0; i < 4; ++i) {       // 4 consecutive tokens per write
                    f16x4_t v;
#pragma unroll
                    for (int r = 0; r < 4; ++r) v[r] = (_Float16)acc[i][j][r];
                    *(f16x4_t*)&tlw[ln * 68 + i * 16 + qd * 4] = v;
                }
                // same-wave RAW/WAR through LDS: compiler orders + inserts lgkm waits
#pragma unroll
                for (int e = 0; e < 2; ++e) {
                    const int ci = lane * 2 + e;    // 0..127 = (d_local 0..15, w 0..7)
                    const int dl = ci >> 3, w2 = ci & 7;
                    const int pq = w2 ^ (dl & 7);
                    const int base = (pq >> 2) * 32 + (pq & 3) * 4;
                    f16x4_t v0 = *(const f16x4_t*)&tlw[dl * 68 + base];
                    f16x4_t v1 = *(const f16x4_t*)&tlw[dl * 68 + base + 16];
                    f16x8_t val = __builtin_shufflevector(v0, v1, 0, 1, 2, 3, 4, 5, 6, 7);
                    *(f16x8_t*)&VTg[obase + (size_t)((j * 16 + dl) * 8 + w2) * 8] = val;
                }
            }
            return;
        }
        // Q or K third: per-head LayerNorm (+ 8*log2e pre-scale on Q)
        {
            const float scale = (n0 < 1024) ? 8.0f * LOG2E : 1.0f;
            float lw[4], lb[4];
#pragma unroll
            for (int j = 0; j < 4; ++j) { lw[j] = ln_w[j * 16 + ln]; lb[j] = ln_b[j * 16 + ln]; }
#pragma unroll
            for (int i = 0; i < 4; ++i)
#pragma unroll
                for (int r = 0; r < 4; ++r) {
                    float s = acc[i][0][r] + acc[i][1][r] + acc[i][2][r] + acc[i][3][r];
                    s += __shfl_xor(s, 1); s += __shfl_xor(s, 2);
                    s += __shfl_xor(s, 4); s += __shfl_xor(s, 8);
                    const float mu = s * 0.015625f;
                    const float d0 = acc[i][0][r] - mu, d1 = acc[i][1][r] - mu;
                    const float d2 = acc[i][2][r] - mu, d3 = acc[i][3][r] - mu;
                    float v = d0 * d0 + d1 * d1 + d2 * d2 + d3 * d3;
                    v += __shfl_xor(v, 1); v += __shfl_xor(v, 2);
                    v += __shfl_xor(v, 4); v += __shfl_xor(v, 8);
                    const float rs = rsqrtf(v * 0.015625f + 1e-5f);
                    acc[i][0][r] = (d0 * rs * lw[0] + lb[0]) * scale;
                    acc[i][1][r] = (d1 * rs * lw[1] + lb[1]) * scale;
                    acc[i][2][r] = (d2 * rs * lw[2] + lb[2]) * scale;
                    acc[i][3][r] = (d3 * rs * lw[3] + lb[3]) * scale;
                }
        }
    }

#pragma unroll
    for (int i = 0; i < 4; ++i)
#pragma unroll
        for (int j = 0; j < 4; ++j) {
            const int col = n0 + wn + j * 16 + ln;
            const float bv = BIAS ? bias[col] : 0.0f;
#pragma unroll
            for (int r = 0; r < 4; ++r) {
                const int row = m0 + wm + i * 16 + qd * 4 + r;
                C[(size_t)row * N + col] = (OutT)(acc[i][j][r] + bv);
            }
        }
}

// ---------------- GEMM 64x128 tile variant (small-N proj), R4 structure ----------------
__global__ __launch_bounds__(256, 2)
void gemm_f16_m64_k(const _Float16* __restrict__ A, const _Float16* __restrict__ BT,
                    float* __restrict__ C, const float* __restrict__ bias,
                    int M, int N, int K) {
    __shared__ _Float16 As[2][64][32];
    __shared__ _Float16 Bs[2][128][32];
    const int tid = threadIdx.x;
    const int wid = tid >> 6, lane = tid & 63;
    const int qd = lane >> 4, ln = lane & 15;
    const int m0 = blockIdx.x * 64, n0 = blockIdx.y * 128;
    const int wn = wid * 32;

    f32x4_t acc[4][2] = {};
    const int srow = lane >> 2;
    const int skk  = (lane & 3) * 8;

    for (int k0 = 0; k0 < K; k0 += 64) {
        __syncthreads();
#pragma unroll
        for (int p = 0; p < 2; ++p) {         // A: 8 segs
            const int seg = p * 4 + wid;
            const int hidx = seg * 512 + lane * 8;
            const int s_ = hidx >> 11;
            const int row = (hidx >> 5) & 63;
            const int kk = hidx & 31;
            async_copy16(&As[0][0][0] + seg * 512,
                         A + (size_t)(m0 + row) * K + k0 + s_ * 32 + kk);
        }
#pragma unroll
        for (int p = 0; p < 4; ++p) {         // B: 16 segs
            const int seg = p * 4 + wid;
            const int s   = seg >> 3;
            const int rg  = seg & 7;
            const int row = rg * 16 + srow;
            async_copy16(&Bs[0][0][0] + seg * 512,
                         BT + (size_t)(n0 + row) * K + k0 + s * 32 + skk);
        }
        __syncthreads();
#pragma unroll
        for (int s = 0; s < 2; ++s) {
            f16x8_t a[4], b[2];
#pragma unroll
            for (int i = 0; i < 4; ++i)
                a[i] = *(const f16x8_t*)&As[s][i * 16 + ln][qd * 8];
#pragma unroll
            for (int j = 0; j < 2; ++j)
                b[j] = *(const f16x8_t*)&Bs[s][wn + j * 16 + ln][qd * 8];
#pragma unroll
            for (int i = 0; i < 4; ++i)
#pragma unroll
                for (int j = 0; j < 2; ++j)
                    acc[i][j] = MFMA32(a[i], b[j], acc[i][j]);
        }
    }
#pragma unroll
    for (int i = 0; i < 4; ++i)
#pragma unroll
        for (int j = 0; j < 2; ++j) {
            const int col = n0 + wn + j * 16 + ln;
            const float bv = bias[col];
#pragma unroll
            for (int r = 0; r < 4; ++r) {
                const int row = m0 + i * 16 + qd * 4 + r;
                C[(size_t)row * N + col] = acc[i][j][r] + bv;
            }
        }
}

// ---------------- flash attention, 32 q-rows/wave, 128-row bands, split-KV ----------------
// R3 structure verbatim (proven 51.2us): grid (32 bh, 24 units), bounds(256,3),
// 2 LDS buffers, __syncthreads per step, prefetch issued post-barrier.
__global__ __launch_bounds__(256, 3)
void attn_part_k(const _Float16* __restrict__ qkv, const _Float16* __restrict__ VTg,
                 _Float16* __restrict__ O, float* __restrict__ Op, float* __restrict__ ml) {
    __shared__ _Float16 Ks[2][2][64][32];   // [buf][plane][kv][k]  16KB
    __shared__ _Float16 VT[2][64][64];      // [buf][d][pre-baked cells] 16KB

    const int tid = threadIdx.x;
    const int wid = tid >> 6, lane = tid & 63;
    const int qd = lane >> 4, ln = lane & 15;
    const int bh = blockIdx.x;
    const int b = bh >> 4, h = bh & 15;
    const int y = blockIdx.y;
    int band, chunk, nst;
    if (y < 8)       { band = 8 + y;  chunk = 0; nst = 16; }
    else if (y < 16) { band = 23 - y; chunk = 1; nst = 2 * band - 14; }
    else             { band = y - 16; chunk = 0; nst = 2 * band + 2; }
    const size_t vtbase = (size_t)bh * 131072;
    const int qrow0 = band * 128 + wid * 32;
    const int kvbeg = chunk * 1024;

    // Q fragments for both 16-row q-tiles (MFMA B operand of S^T; q=ln, k spread)
    f16x8_t qf[2][2];
#pragma unroll
    for (int qt = 0; qt < 2; ++qt)
#pragma unroll
        for (int s = 0; s < 2; ++s)
            qf[qt][s] = *(const f16x8_t*)&qkv[(size_t)(b * 2048 + qrow0 + qt * 16 + ln) * 3072
                                             + h * 64 + s * 32 + qd * 8];

    f32x4_t o[2][4] = {};
    f32x4_t ls[2] = {};                     // row-sum accumulators; only [0] kept scaled
    float m[2] = { -3.0e38f, -3.0e38f };
    const f16x4_t ones = { (_Float16)1.0f, (_Float16)1.0f, (_Float16)1.0f, (_Float16)1.0f };

    auto stage = [&](int buf, int kv0) {
#pragma unroll
        for (int p = 0; p < 2; ++p) {           // K: 8 segs of 1KB, strided qkv source
            const int seg = p * 4 + wid;
            const int hidx = seg * 512 + lane * 8;
            const int s_ = hidx >> 11;
            const int rrow = (hidx >> 5) & 63;
            const int kk = hidx & 31;
            async_copy16(&Ks[buf][0][0][0] + seg * 512,
                         qkv + (size_t)(b * 2048 + kv0 + rrow) * 3072 + 1024 + h * 64
                             + s_ * 32 + kk);
        }
#pragma unroll
        for (int p = 0; p < 2; ++p) {           // V: pre-baked tile, pure linear copy
            const int seg = p * 4 + wid;
            async_copy16(&VT[buf][0][0] + seg * 512,
                         VTg + vtbase + (size_t)kv0 * 64 + seg * 512 + lane * 8);
        }
    };

    stage(0, kvbeg);

    for (int st = 0; st < nst; ++st) {
        const int kv0 = kvbeg + st * 64;
        __syncthreads();                        // drains staging of buf[st&1]
        if (st + 1 < nst) stage((st + 1) & 1, kv0 + 64);
        const int buf = st & 1;

        if (kv0 <= qrow0 + 31) {                // wave has >=1 unmasked score
            // S^T = K Q^T for both q-tiles (kb transient: 8 regs at a time)
            f32x4_t sc[2][4];
#pragma unroll
            for (int jt = 0; jt < 4; ++jt) {
                f16x8_t k0 = *(const f16x8_t*)&Ks[buf][0][jt * 16 + ln][qd * 8];
                f16x8_t k1 = *(const f16x8_t*)&Ks[buf][1][jt * 16 + ln][qd * 8];
#pragma unroll
                for (int qt = 0; qt < 2; ++qt) {
                    f32x4_t s = {};
                    s = MFMA32(k0, qf[qt][0], s);
                    s = MFMA32(k1, qf[qt][1], s);
                    sc[qt][jt] = s;
                }
            }
            // V fragments (reused by both q-tiles)
            f16x8_t vf8[4][2];                  // [dt][pp]: b128 from pre-baked cell
#pragma unroll
            for (int dt = 0; dt < 4; ++dt)
#pragma unroll
                for (int pp = 0; pp < 2; ++pp) {
                    const int w = (pp * 4 + qd) ^ (ln & 7);
                    vf8[dt][pp] = *(const f16x8_t*)&VT[buf][dt * 16 + ln][w * 8];
                }

#pragma unroll
            for (int qt = 0; qt < 2; ++qt) {
                if (kv0 + 63 > qrow0 + qt * 16) {       // (partially) masked tile row-band
                    const int qq = qrow0 + qt * 16 + ln;
#pragma unroll
                    for (int c = 0; c < 4; ++c)
#pragma unroll
                        for (int r = 0; r < 4; ++r)
                            if (kv0 + c * 16 + qd * 4 + r > qq) sc[qt][c][r] = -3.0e38f;
                }
                // max over this lane's 16 scores (max3-fusable chains), then quarters
                float mx0 = fmaxf(fmaxf(fmaxf(sc[qt][0][0], sc[qt][1][0]), sc[qt][2][0]), sc[qt][3][0]);
                float mx1 = fmaxf(fmaxf(fmaxf(sc[qt][0][1], sc[qt][1][1]), sc[qt][2][1]), sc[qt][3][1]);
                float mx2 = fmaxf(fmaxf(fmaxf(sc[qt][0][2], sc[qt][1][2]), sc[qt][2][2]), sc[qt][3][2]);
                float mx3 = fmaxf(fmaxf(fmaxf(sc[qt][0][3], sc[qt][1][3]), sc[qt][2][3]), sc[qt][3][3]);
                float mx = fmaxf(fmaxf(fmaxf(mx0, mx1), mx2), mx3);
                mx = fmaxf(mx, __shfl_xor(mx, 16));
                mx = fmaxf(mx, __shfl_xor(mx, 32));
                // defer-max: rescale only when tile max beats running max by >8 (log2)
                if (!__all(mx <= m[qt] + 8.0f)) {
                    const float mn = fmaxf(m[qt], mx);
                    const float al = exp2f(m[qt] - mn);
#pragma unroll
                    for (int dt = 0; dt < 4; ++dt) o[qt][dt] *= al;
                    ls[qt][0] *= al;
                    m[qt] = mn;
                }
                f16x4_t pf[4];
#pragma unroll
                for (int c = 0; c < 4; ++c) {
                    float p0 = exp2f(sc[qt][c][0] - m[qt]);
                    float p1 = exp2f(sc[qt][c][1] - m[qt]);
                    float p2 = exp2f(sc[qt][c][2] - m[qt]);
                    float p3 = exp2f(sc[qt][c][3] - m[qt]);
                    f16x2_t a = __builtin_bit_cast(f16x2_t, __builtin_amdgcn_cvt_pkrtz(p0, p1));
                    f16x2_t bb = __builtin_bit_cast(f16x2_t, __builtin_amdgcn_cvt_pkrtz(p2, p3));
                    pf[c] = __builtin_shufflevector(a, bb, 0, 1, 2, 3);
                }
                // row sums + PV on the MFMA pipe (T5: boost while in pure-MFMA cluster)
                __builtin_amdgcn_s_setprio(1);
#pragma unroll
                for (int c = 0; c < 4; ++c) ls[qt] = MFMA16(ones, pf[c], ls[qt]);
#pragma unroll
                for (int dt = 0; dt < 4; ++dt)
#pragma unroll
                    for (int pp = 0; pp < 2; ++pp) {
                        f16x4_t lo = __builtin_shufflevector(vf8[dt][pp], vf8[dt][pp], 0, 1, 2, 3);
                        f16x4_t hi = __builtin_shufflevector(vf8[dt][pp], vf8[dt][pp], 4, 5, 6, 7);
                        o[qt][dt] = MFMA16(lo, pf[pp * 2 + 0], o[qt][dt]);
                        o[qt][dt] = MFMA16(hi, pf[pp * 2 + 1], o[qt][dt]);
                    }
                __builtin_amdgcn_s_setprio(0);
            }
        }
    }

    if (band < 8) {                             // final output (rows 0..1023)
        const size_t base0 = ((size_t)(b * 2048 + qrow0 + ln)) * 1024 + h * 64 + qd * 4;
#pragma unroll
        for (int qt = 0; qt < 2; ++qt) {
            const float inv = 1.0f / ls[qt][0];
            const size_t base = base0 + (size_t)qt * 16 * 1024;
#pragma unroll
            for (int dt = 0; dt < 4; ++dt) {
                f16x4_t ov;
#pragma unroll
                for (int r = 0; r < 4; ++r) ov[r] = (_Float16)(o[qt][dt][r] * inv);
                *(f16x4_t*)&O[base + dt * 16] = ov;
            }
        }
    } else {                                    // fp32 partial (rows 1024..2047, 2 chunks)
        const size_t pb = ((size_t)bh * 8 + (band - 8)) * 2 + chunk;
#pragma unroll
        for (int qt = 0; qt < 2; ++qt) {
            const int row = wid * 32 + qt * 16 + ln;
            float* op = Op + pb * 8192 + (size_t)row * 64 + qd * 4;
#pragma unroll
            for (int dt = 0; dt < 4; ++dt)
                *(f32x4_t*)&op[dt * 16] = o[qt][dt];
            if (qd == 0) {
                ml[pb * 256 + row * 2]     = m[qt];
                ml[pb * 256 + row * 2 + 1] = ls[qt][0];
            }
        }
    }
}

// ---------------- merge two split-KV partials (bands 8..15, 128 rows each) ----------------
__global__ __launch_bounds__(256)
void attn_merge_k(const float* __restrict__ Op, const float* __restrict__ ml,
                  _Float16* __restrict__ O) {
    const int bh = blockIdx.x, bnd = blockIdx.y;    // bnd 0..7 -> band 8+bnd
    const int b = bh >> 4, h = bh & 15;
    const int band = 8 + bnd;
    const size_t pb = ((size_t)bh * 8 + bnd) * 2;
    const int tid = threadIdx.x;
    const int row = tid >> 1;                       // 0..127
    const int c32 = (tid & 1) * 32;
    const float m0 = ml[pb * 256 + row * 2],       l0 = ml[pb * 256 + row * 2 + 1];
    const float m1 = ml[(pb + 1) * 256 + row * 2], l1 = ml[(pb + 1) * 256 + row * 2 + 1];
    const float mm = fmaxf(m0, m1);
    const float a0 = exp2f(m0 - mm), a1 = exp2f(m1 - mm);
    const float inv = 1.0f / (l0 * a0 + l1 * a1);
    const float* p0 = Op + pb * 8192 + (size_t)row * 64 + c32;
    const float* p1 = p0 + 8192;
    _Float16* op = O + ((size_t)(b * 2048 + band * 128 + row)) * 1024 + h * 64 + c32;
#pragma unroll
    for (int g = 0; g < 8; ++g) {
        f32x4_t v0 = *(const f32x4_t*)&p0[g * 4];
        f32x4_t v1 = *(const f32x4_t*)&p1[g * 4];
        f16x4_t ov;
#pragma unroll
        for (int r = 0; r < 4; ++r)
            ov[r] = (_Float16)((v0[r] * a0 + v1[r] * a1) * inv);
        *(f16x4_t*)&op[g * 4] = ov;
    }
}

extern "C" void kernel_launch(void* const* d_in, const int* in_sizes, int n_in,
                              void* d_out, int out_size, void* d_ws, size_t ws_size,
                              hipStream_t stream) {
    const float* x      = (const float*)d_in[0];
    const float* w_qkv  = (const float*)d_in[1];
    const float* w_proj = (const float*)d_in[2];
    const float* b_proj = (const float*)d_in[3];
    const float* ln_w   = (const float*)d_in[4];
    const float* ln_b   = (const float*)d_in[5];
    float* out = (float*)d_out;

    // workspace partition (~73 MB), no aliasing
    char* w = (char*)d_ws;
    const size_t MB = 1024 * 1024;
    _Float16*  qkv    = (_Float16*)(w);             // 24 MB (Q,K LN'd; V third unused)
    _Float16*  xh     = (_Float16*)(w + 24 * MB);   //  8 MB
    _Float16*  wqkvT  = (_Float16*)(w + 32 * MB);   //  6 MB
    _Float16*  wprojT = (_Float16*)(w + 38 * MB);   //  2 MB
    _Float16*  VTg    = (_Float16*)(w + 40 * MB);   //  8 MB
    _Float16*  Ah     = (_Float16*)(w + 48 * MB);   //  8 MB
    float*     Op     = (float*)(w + 56 * MB);      // 16 MB (32*8*2 slots * 8192 f32)
    float*     mlb    = (float*)(w + 72 * MB);      // 0.5 MB

    prep_k<<<5120, 256, 0, stream>>>(x, xh, w_qkv, wqkvT, w_proj, wprojT);
    gemm_f16_k<_Float16, false, true><<<dim3(32, 24), 256, 0, stream>>>(
        xh, wqkvT, qkv, nullptr, VTg, ln_w, ln_b, 4096, 3072, 1024);
    attn_part_k<<<dim3(32, 24), 256, 0, stream>>>(qkv, VTg, Ah, Op, mlb);
    attn_merge_k<<<dim3(32, 8), 256, 0, stream>>>(Op, mlb, Ah);
    gemm_f16_m64_k<<<dim3(64, 8), 256, 0, stream>>>(Ah, wprojT, out, b_proj, 4096, 1024, 1024);
}

// Round 13
// 189.341 us; speedup vs baseline: 1.0528x; 1.0528x over previous
//
#include <hip/hip_runtime.h>

#define LOG2E 1.4426950408889634f

typedef _Float16 f16x8_t __attribute__((ext_vector_type(8)));
typedef _Float16 f16x4_t __attribute__((ext_vector_type(4)));
typedef _Float16 f16x2_t __attribute__((ext_vector_type(2)));
typedef float    f32x4_t __attribute__((ext_vector_type(4)));

#define MFMA32(a, b, c) __builtin_amdgcn_mfma_f32_16x16x32_f16(a, b, c, 0, 0, 0)
#define MFMA16(a, b, c) __builtin_amdgcn_mfma_f32_16x16x16f16(a, b, c, 0, 0, 0)

// async 16B/lane global->LDS copy. LDS dest is wave-uniform base + lane*16.
__device__ __forceinline__ void async_copy16(void* lds, const void* g) {
    __builtin_amdgcn_global_load_lds(
        (const __attribute__((address_space(1))) unsigned char*)g,
        (__attribute__((address_space(3))) unsigned char*)lds, 16, 0, 0);
}

// ---------------- fused prep: cast x->fp16 + transpose-cast both weight mats ----------
// blockIdx.x ranges: [0,4096) cast, [4096,4864) w_qkv 64x64 tiles, [4864,5120) w_proj.
__global__ void prep_k(const float* __restrict__ x, _Float16* __restrict__ xh,
                       const float* __restrict__ wq, _Float16* __restrict__ wqT,
                       const float* __restrict__ wp, _Float16* __restrict__ wpT) {
    __shared__ _Float16 tl[64][65];
    const int bx = blockIdx.x, t = threadIdx.x;
    if (bx < 4096) {
        const int i = bx * 256 + t;
        float4 v = ((const float4*)x)[i];
        f16x4_t o = { (_Float16)v.x, (_Float16)v.y, (_Float16)v.z, (_Float16)v.w };
        ((f16x4_t*)xh)[i] = o;
        return;
    }
    const float* in; _Float16* out; int C, bxx, byy;
    if (bx < 4864) { const int id = bx - 4096; in = wq; out = wqT; C = 3072; bxx = id % 48; byy = id / 48; }
    else           { const int id = bx - 4864; in = wp; out = wpT; C = 1024; bxx = id % 16; byy = id / 16; }
    const int R = 1024;
    const int c = t & 63;
    const int r4 = t >> 6;
    const int r0 = byy * 64, c0 = bxx * 64;
#pragma unroll
    for (int i = 0; i < 16; ++i) {
        int r = r4 + i * 4;
        tl[c][r] = (_Float16)in[(size_t)(r0 + r) * C + c0 + c];
    }
    __syncthreads();
#pragma unroll
    for (int i = 0; i < 16; ++i) {
        int rr = r4 + i * 4;
        out[(size_t)(c0 + rr) * R + r0 + c] = tl[rr][c];
    }
}

// ---------------- GEMM: C[M][N] = A[M][K] * BT[N][K]^T (+bias), fp16 in ----------------
// R4-proven structure: BK=64 staged as two 32-k planes, two barriers per K-step.
// (Structural ledger: beats BK=32-dbuf [R5], BK=64-dbuf @2blk/CU [R12], XCD swizzle [R10].)
// LNQK epilogues (QKV projection):
//  - Q/K thirds (n0<2048): fused per-head LayerNorm; wave's acc = 64 tokens x one head.
//  - V third (n0>=2048): emit pre-baked VTg MFMA tiles DIRECTLY (fused vtrans).
template <typename OutT, bool BIAS, bool LNQK>
__global__ __launch_bounds__(256, 3)
void gemm_f16_k(const _Float16* __restrict__ A, const _Float16* __restrict__ BT,
                OutT* __restrict__ C, const float* __restrict__ bias,
                _Float16* __restrict__ VTg,
                const float* __restrict__ ln_w, const float* __restrict__ ln_b,
                int M, int N, int K) {
    __shared__ _Float16 As[2][128][32];
    __shared__ _Float16 Bs[2][128][32];
    const int tid = threadIdx.x;
    const int wid = tid >> 6, lane = tid & 63;
    const int qd = lane >> 4, ln = lane & 15;
    const int m0 = blockIdx.x * 128, n0 = blockIdx.y * 128;
    const int wm = (wid >> 1) * 64, wn = (wid & 1) * 64;

    f32x4_t acc[4][4] = {};

    const int srow = lane >> 2;
    const int skk  = (lane & 3) * 8;

    for (int k0 = 0; k0 < K; k0 += 64) {
        __syncthreads();
#pragma unroll
        for (int p = 0; p < 4; ++p) {
            const int seg = p * 4 + wid;           // 0..15
            const int s   = seg >> 3;
            const int rg  = seg & 7;
            const int row = rg * 16 + srow;
            const size_t goff = (size_t)row * K + k0 + s * 32 + skk;
            async_copy16(&As[0][0][0] + seg * 512, A  + (size_t)m0 * K + goff);
            async_copy16(&Bs[0][0][0] + seg * 512, BT + (size_t)n0 * K + goff);
        }
        __syncthreads();
#pragma unroll
        for (int s = 0; s < 2; ++s) {
            f16x8_t a[4], b[4];
#pragma unroll
            for (int i = 0; i < 4; ++i)
                a[i] = *(const f16x8_t*)&As[s][wm + i * 16 + ln][qd * 8];
#pragma unroll
            for (int j = 0; j < 4; ++j)
                b[j] = *(const f16x8_t*)&Bs[s][wn + j * 16 + ln][qd * 8];
#pragma unroll
            for (int i = 0; i < 4; ++i)
#pragma unroll
                for (int j = 0; j < 4; ++j)
                    acc[i][j] = MFMA32(a[i], b[j], acc[i][j]);
        }
    }

    if constexpr (LNQK) {
        if (n0 >= 2048) {                           // V third -> VTg (vtrans fused)
            __syncthreads();                        // safe to reuse As as scratch
            const int h2  = ((n0 - 2048) >> 6) + (wn >> 6);
            const int row0 = m0 + wm;               // 64-token aligned
            const int bb  = row0 >> 11;
            const int tt  = (row0 & 2047) >> 6;
            const size_t obase = ((size_t)(bb * 16 + h2)) * 131072 + (size_t)tt * 4096;
            _Float16* tlw = &As[0][0][0] + wid * 1088;   // 16 rows x 68 halfs per wave
#pragma unroll
            for (int j = 0; j < 4; ++j) {           // d-group j*16 .. j*16+15
#pragma unroll
                for (int i = 0; i < 4; ++i) {       // 4 consecutive tokens per write
                    f16x4_t v;
#pragma unroll
                    for (int r = 0; r < 4; ++r) v[r] = (_Float16)acc[i][j][r];
                    *(f16x4_t*)&tlw[ln * 68 + i * 16 + qd * 4] = v;
                }
                // same-wave RAW/WAR through LDS: compiler orders + inserts lgkm waits
#pragma unroll
                for (int e = 0; e < 2; ++e) {
                    const int ci = lane * 2 + e;    // 0..127 = (d_local 0..15, w 0..7)
                    const int dl = ci >> 3, w2 = ci & 7;
                    const int pq = w2 ^ (dl & 7);
                    const int base = (pq >> 2) * 32 + (pq & 3) * 4;
                    f16x4_t v0 = *(const f16x4_t*)&tlw[dl * 68 + base];
                    f16x4_t v1 = *(const f16x4_t*)&tlw[dl * 68 + base + 16];
                    f16x8_t val = __builtin_shufflevector(v0, v1, 0, 1, 2, 3, 4, 5, 6, 7);
                    *(f16x8_t*)&VTg[obase + (size_t)((j * 16 + dl) * 8 + w2) * 8] = val;
                }
            }
            return;
        }
        // Q or K third: per-head LayerNorm (+ 8*log2e pre-scale on Q)
        {
            const float scale = (n0 < 1024) ? 8.0f * LOG2E : 1.0f;
            float lw[4], lb[4];
#pragma unroll
            for (int j = 0; j < 4; ++j) { lw[j] = ln_w[j * 16 + ln]; lb[j] = ln_b[j * 16 + ln]; }
#pragma unroll
            for (int i = 0; i < 4; ++i)
#pragma unroll
                for (int r = 0; r < 4; ++r) {
                    float s = acc[i][0][r] + acc[i][1][r] + acc[i][2][r] + acc[i][3][r];
                    s += __shfl_xor(s, 1); s += __shfl_xor(s, 2);
                    s += __shfl_xor(s, 4); s += __shfl_xor(s, 8);
                    const float mu = s * 0.015625f;
                    const float d0 = acc[i][0][r] - mu, d1 = acc[i][1][r] - mu;
                    const float d2 = acc[i][2][r] - mu, d3 = acc[i][3][r] - mu;
                    float v = d0 * d0 + d1 * d1 + d2 * d2 + d3 * d3;
                    v += __shfl_xor(v, 1); v += __shfl_xor(v, 2);
                    v += __shfl_xor(v, 4); v += __shfl_xor(v, 8);
                    const float rs = rsqrtf(v * 0.015625f + 1e-5f);
                    acc[i][0][r] = (d0 * rs * lw[0] + lb[0]) * scale;
                    acc[i][1][r] = (d1 * rs * lw[1] + lb[1]) * scale;
                    acc[i][2][r] = (d2 * rs * lw[2] + lb[2]) * scale;
                    acc[i][3][r] = (d3 * rs * lw[3] + lb[3]) * scale;
                }
        }
    }

#pragma unroll
    for (int i = 0; i < 4; ++i)
#pragma unroll
        for (int j = 0; j < 4; ++j) {
            const int col = n0 + wn + j * 16 + ln;
            const float bv = BIAS ? bias[col] : 0.0f;
#pragma unroll
            for (int r = 0; r < 4; ++r) {
                const int row = m0 + wm + i * 16 + qd * 4 + r;
                C[(size_t)row * N + col] = (OutT)(acc[i][j][r] + bv);
            }
        }
}

// ---------------- GEMM 64x128 tile variant (small-N proj), R4 structure ----------------
__global__ __launch_bounds__(256, 2)
void gemm_f16_m64_k(const _Float16* __restrict__ A, const _Float16* __restrict__ BT,
                    float* __restrict__ C, const float* __restrict__ bias,
                    int M, int N, int K) {
    __shared__ _Float16 As[2][64][32];
    __shared__ _Float16 Bs[2][128][32];
    const int tid = threadIdx.x;
    const int wid = tid >> 6, lane = tid & 63;
    const int qd = lane >> 4, ln = lane & 15;
    const int m0 = blockIdx.x * 64, n0 = blockIdx.y * 128;
    const int wn = wid * 32;

    f32x4_t acc[4][2] = {};
    const int srow = lane >> 2;
    const int skk  = (lane & 3) * 8;

    for (int k0 = 0; k0 < K; k0 += 64) {
        __syncthreads();
#pragma unroll
        for (int p = 0; p < 2; ++p) {         // A: 8 segs
            const int seg = p * 4 + wid;
            const int hidx = seg * 512 + lane * 8;
            const int s_ = hidx >> 11;
            const int row = (hidx >> 5) & 63;
            const int kk = hidx & 31;
            async_copy16(&As[0][0][0] + seg * 512,
                         A + (size_t)(m0 + row) * K + k0 + s_ * 32 + kk);
        }
#pragma unroll
        for (int p = 0; p < 4; ++p) {         // B: 16 segs
            const int seg = p * 4 + wid;
            const int s   = seg >> 3;
            const int rg  = seg & 7;
            const int row = rg * 16 + srow;
            async_copy16(&Bs[0][0][0] + seg * 512,
                         BT + (size_t)(n0 + row) * K + k0 + s * 32 + skk);
        }
        __syncthreads();
#pragma unroll
        for (int s = 0; s < 2; ++s) {
            f16x8_t a[4], b[2];
#pragma unroll
            for (int i = 0; i < 4; ++i)
                a[i] = *(const f16x8_t*)&As[s][i * 16 + ln][qd * 8];
#pragma unroll
            for (int j = 0; j < 2; ++j)
                b[j] = *(const f16x8_t*)&Bs[s][wn + j * 16 + ln][qd * 8];
#pragma unroll
            for (int i = 0; i < 4; ++i)
#pragma unroll
                for (int j = 0; j < 2; ++j)
                    acc[i][j] = MFMA32(a[i], b[j], acc[i][j]);
        }
    }
#pragma unroll
    for (int i = 0; i < 4; ++i)
#pragma unroll
        for (int j = 0; j < 2; ++j) {
            const int col = n0 + wn + j * 16 + ln;
            const float bv = bias[col];
#pragma unroll
            for (int r = 0; r < 4; ++r) {
                const int row = m0 + i * 16 + qd * 4 + r;
                C[(size_t)row * N + col] = acc[i][j][r] + bv;
            }
        }
}

// ---------------- flash attention, 32 q-rows/wave, 128-row bands, split-KV ----------------
// R3 structure verbatim (proven 51.2us): grid (32 bh, 24 units), bounds(256,3),
// 2 LDS buffers, __syncthreads per step, prefetch issued post-barrier.
__global__ __launch_bounds__(256, 3)
void attn_part_k(const _Float16* __restrict__ qkv, const _Float16* __restrict__ VTg,
                 _Float16* __restrict__ O, float* __restrict__ Op, float* __restrict__ ml) {
    __shared__ _Float16 Ks[2][2][64][32];   // [buf][plane][kv][k]  16KB
    __shared__ _Float16 VT[2][64][64];      // [buf][d][pre-baked cells] 16KB

    const int tid = threadIdx.x;
    const int wid = tid >> 6, lane = tid & 63;
    const int qd = lane >> 4, ln = lane & 15;
    const int bh = blockIdx.x;
    const int b = bh >> 4, h = bh & 15;
    const int y = blockIdx.y;
    int band, chunk, nst;
    if (y < 8)       { band = 8 + y;  chunk = 0; nst = 16; }
    else if (y < 16) { band = 23 - y; chunk = 1; nst = 2 * band - 14; }
    else             { band = y - 16; chunk = 0; nst = 2 * band + 2; }
    const size_t vtbase = (size_t)bh * 131072;
    const int qrow0 = band * 128 + wid * 32;
    const int kvbeg = chunk * 1024;

    // Q fragments for both 16-row q-tiles (MFMA B operand of S^T; q=ln, k spread)
    f16x8_t qf[2][2];
#pragma unroll
    for (int qt = 0; qt < 2; ++qt)
#pragma unroll
        for (int s = 0; s < 2; ++s)
            qf[qt][s] = *(const f16x8_t*)&qkv[(size_t)(b * 2048 + qrow0 + qt * 16 + ln) * 3072
                                             + h * 64 + s * 32 + qd * 8];

    f32x4_t o[2][4] = {};
    f32x4_t ls[2] = {};                     // row-sum accumulators; only [0] kept scaled
    float m[2] = { -3.0e38f, -3.0e38f };
    const f16x4_t ones = { (_Float16)1.0f, (_Float16)1.0f, (_Float16)1.0f, (_Float16)1.0f };

    auto stage = [&](int buf, int kv0) {
#pragma unroll
        for (int p = 0; p < 2; ++p) {           // K: 8 segs of 1KB, strided qkv source
            const int seg = p * 4 + wid;
            const int hidx = seg * 512 + lane * 8;
            const int s_ = hidx >> 11;
            const int rrow = (hidx >> 5) & 63;
            const int kk = hidx & 31;
            async_copy16(&Ks[buf][0][0][0] + seg * 512,
                         qkv + (size_t)(b * 2048 + kv0 + rrow) * 3072 + 1024 + h * 64
                             + s_ * 32 + kk);
        }
#pragma unroll
        for (int p = 0; p < 2; ++p) {           // V: pre-baked tile, pure linear copy
            const int seg = p * 4 + wid;
            async_copy16(&VT[buf][0][0] + seg * 512,
                         VTg + vtbase + (size_t)kv0 * 64 + seg * 512 + lane * 8);
        }
    };

    stage(0, kvbeg);

    for (int st = 0; st < nst; ++st) {
        const int kv0 = kvbeg + st * 64;
        __syncthreads();                        // drains staging of buf[st&1]
        if (st + 1 < nst) stage((st + 1) & 1, kv0 + 64);
        const int buf = st & 1;

        if (kv0 <= qrow0 + 31) {                // wave has >=1 unmasked score
            // S^T = K Q^T for both q-tiles (kb transient: 8 regs at a time)
            f32x4_t sc[2][4];
#pragma unroll
            for (int jt = 0; jt < 4; ++jt) {
                f16x8_t k0 = *(const f16x8_t*)&Ks[buf][0][jt * 16 + ln][qd * 8];
                f16x8_t k1 = *(const f16x8_t*)&Ks[buf][1][jt * 16 + ln][qd * 8];
#pragma unroll
                for (int qt = 0; qt < 2; ++qt) {
                    f32x4_t s = {};
                    s = MFMA32(k0, qf[qt][0], s);
                    s = MFMA32(k1, qf[qt][1], s);
                    sc[qt][jt] = s;
                }
            }
            // V fragments (reused by both q-tiles)
            f16x8_t vf8[4][2];                  // [dt][pp]: b128 from pre-baked cell
#pragma unroll
            for (int dt = 0; dt < 4; ++dt)
#pragma unroll
                for (int pp = 0; pp < 2; ++pp) {
                    const int w = (pp * 4 + qd) ^ (ln & 7);
                    vf8[dt][pp] = *(const f16x8_t*)&VT[buf][dt * 16 + ln][w * 8];
                }

#pragma unroll
            for (int qt = 0; qt < 2; ++qt) {
                if (kv0 + 63 > qrow0 + qt * 16) {       // (partially) masked tile row-band
                    const int qq = qrow0 + qt * 16 + ln;
#pragma unroll
                    for (int c = 0; c < 4; ++c)
#pragma unroll
                        for (int r = 0; r < 4; ++r)
                            if (kv0 + c * 16 + qd * 4 + r > qq) sc[qt][c][r] = -3.0e38f;
                }
                // max over this lane's 16 scores (max3-fusable chains), then quarters
                float mx0 = fmaxf(fmaxf(fmaxf(sc[qt][0][0], sc[qt][1][0]), sc[qt][2][0]), sc[qt][3][0]);
                float mx1 = fmaxf(fmaxf(fmaxf(sc[qt][0][1], sc[qt][1][1]), sc[qt][2][1]), sc[qt][3][1]);
                float mx2 = fmaxf(fmaxf(fmaxf(sc[qt][0][2], sc[qt][1][2]), sc[qt][2][2]), sc[qt][3][2]);
                float mx3 = fmaxf(fmaxf(fmaxf(sc[qt][0][3], sc[qt][1][3]), sc[qt][2][3]), sc[qt][3][3]);
                float mx = fmaxf(fmaxf(fmaxf(mx0, mx1), mx2), mx3);
                mx = fmaxf(mx, __shfl_xor(mx, 16));
                mx = fmaxf(mx, __shfl_xor(mx, 32));
                // defer-max: rescale only when tile max beats running max by >8 (log2)
                if (!__all(mx <= m[qt] + 8.0f)) {
                    const float mn = fmaxf(m[qt], mx);
                    const float al = exp2f(m[qt] - mn);
#pragma unroll
                    for (int dt = 0; dt < 4; ++dt) o[qt][dt] *= al;
                    ls[qt][0] *= al;
                    m[qt] = mn;
                }
                f16x4_t pf[4];
#pragma unroll
                for (int c = 0; c < 4; ++c) {
                    float p0 = exp2f(sc[qt][c][0] - m[qt]);
                    float p1 = exp2f(sc[qt][c][1] - m[qt]);
                    float p2 = exp2f(sc[qt][c][2] - m[qt]);
                    float p3 = exp2f(sc[qt][c][3] - m[qt]);
                    f16x2_t a = __builtin_bit_cast(f16x2_t, __builtin_amdgcn_cvt_pkrtz(p0, p1));
                    f16x2_t bb = __builtin_bit_cast(f16x2_t, __builtin_amdgcn_cvt_pkrtz(p2, p3));
                    pf[c] = __builtin_shufflevector(a, bb, 0, 1, 2, 3);
                }
                // row sums + PV on the MFMA pipe (T5: boost while in pure-MFMA cluster)
                __builtin_amdgcn_s_setprio(1);
#pragma unroll
                for (int c = 0; c < 4; ++c) ls[qt] = MFMA16(ones, pf[c], ls[qt]);
#pragma unroll
                for (int dt = 0; dt < 4; ++dt)
#pragma unroll
                    for (int pp = 0; pp < 2; ++pp) {
                        f16x4_t lo = __builtin_shufflevector(vf8[dt][pp], vf8[dt][pp], 0, 1, 2, 3);
                        f16x4_t hi = __builtin_shufflevector(vf8[dt][pp], vf8[dt][pp], 4, 5, 6, 7);
                        o[qt][dt] = MFMA16(lo, pf[pp * 2 + 0], o[qt][dt]);
                        o[qt][dt] = MFMA16(hi, pf[pp * 2 + 1], o[qt][dt]);
                    }
                __builtin_amdgcn_s_setprio(0);
            }
        }
    }

    if (band < 8) {                             // final output (rows 0..1023)
        const size_t base0 = ((size_t)(b * 2048 + qrow0 + ln)) * 1024 + h * 64 + qd * 4;
#pragma unroll
        for (int qt = 0; qt < 2; ++qt) {
            const float inv = 1.0f / ls[qt][0];
            const size_t base = base0 + (size_t)qt * 16 * 1024;
#pragma unroll
            for (int dt = 0; dt < 4; ++dt) {
                f16x4_t ov;
#pragma unroll
                for (int r = 0; r < 4; ++r) ov[r] = (_Float16)(o[qt][dt][r] * inv);
                *(f16x4_t*)&O[base + dt * 16] = ov;
            }
        }
    } else {                                    // fp32 partial (rows 1024..2047, 2 chunks)
        const size_t pb = ((size_t)bh * 8 + (band - 8)) * 2 + chunk;
#pragma unroll
        for (int qt = 0; qt < 2; ++qt) {
            const int row = wid * 32 + qt * 16 + ln;
            float* op = Op + pb * 8192 + (size_t)row * 64 + qd * 4;
#pragma unroll
            for (int dt = 0; dt < 4; ++dt)
                *(f32x4_t*)&op[dt * 16] = o[qt][dt];
            if (qd == 0) {
                ml[pb * 256 + row * 2]     = m[qt];
                ml[pb * 256 + row * 2 + 1] = ls[qt][0];
            }
        }
    }
}

// ---------------- merge two split-KV partials (bands 8..15, 128 rows each) ----------------
__global__ __launch_bounds__(256)
void attn_merge_k(const float* __restrict__ Op, const float* __restrict__ ml,
                  _Float16* __restrict__ O) {
    const int bh = blockIdx.x, bnd = blockIdx.y;    // bnd 0..7 -> band 8+bnd
    const int b = bh >> 4, h = bh & 15;
    const int band = 8 + bnd;
    const size_t pb = ((size_t)bh * 8 + bnd) * 2;
    const int tid = threadIdx.x;
    const int row = tid >> 1;                       // 0..127
    const int c32 = (tid & 1) * 32;
    const float m0 = ml[pb * 256 + row * 2],       l0 = ml[pb * 256 + row * 2 + 1];
    const float m1 = ml[(pb + 1) * 256 + row * 2], l1 = ml[(pb + 1) * 256 + row * 2 + 1];
    const float mm = fmaxf(m0, m1);
    const float a0 = exp2f(m0 - mm), a1 = exp2f(m1 - mm);
    const float inv = 1.0f / (l0 * a0 + l1 * a1);
    const float* p0 = Op + pb * 8192 + (size_t)row * 64 + c32;
    const float* p1 = p0 + 8192;
    _Float16* op = O + ((size_t)(b * 2048 + band * 128 + row)) * 1024 + h * 64 + c32;
#pragma unroll
    for (int g = 0; g < 8; ++g) {
        f32x4_t v0 = *(const f32x4_t*)&p0[g * 4];
        f32x4_t v1 = *(const f32x4_t*)&p1[g * 4];
        f16x4_t ov;
#pragma unroll
        for (int r = 0; r < 4; ++r)
            ov[r] = (_Float16)((v0[r] * a0 + v1[r] * a1) * inv);
        *(f16x4_t*)&op[g * 4] = ov;
    }
}

extern "C" void kernel_launch(void* const* d_in, const int* in_sizes, int n_in,
                              void* d_out, int out_size, void* d_ws, size_t ws_size,
                              hipStream_t stream) {
    const float* x      = (const float*)d_in[0];
    const float* w_qkv  = (const float*)d_in[1];
    const float* w_proj = (const float*)d_in[2];
    const float* b_proj = (const float*)d_in[3];
    const float* ln_w   = (const float*)d_in[4];
    const float* ln_b   = (const float*)d_in[5];
    float* out = (float*)d_out;

    // workspace partition (~73 MB), no aliasing
    char* w = (char*)d_ws;
    const size_t MB = 1024 * 1024;
    _Float16*  qkv    = (_Float16*)(w);             // 24 MB (Q,K LN'd; V third unused)
    _Float16*  xh     = (_Float16*)(w + 24 * MB);   //  8 MB
    _Float16*  wqkvT  = (_Float16*)(w + 32 * MB);   //  6 MB
    _Float16*  wprojT = (_Float16*)(w + 38 * MB);   //  2 MB
    _Float16*  VTg    = (_Float16*)(w + 40 * MB);   //  8 MB
    _Float16*  Ah     = (_Float16*)(w + 48 * MB);   //  8 MB
    float*     Op     = (float*)(w + 56 * MB);      // 16 MB (32*8*2 slots * 8192 f32)
    float*     mlb    = (float*)(w + 72 * MB);      // 0.5 MB

    prep_k<<<5120, 256, 0, stream>>>(x, xh, w_qkv, wqkvT, w_proj, wprojT);
    gemm_f16_k<_Float16, false, true><<<dim3(32, 24), 256, 0, stream>>>(
        xh, wqkvT, qkv, nullptr, VTg, ln_w, ln_b, 4096, 3072, 1024);
    attn_part_k<<<dim3(32, 24), 256, 0, stream>>>(qkv, VTg, Ah, Op, mlb);
    attn_merge_k<<<dim3(32, 8), 256, 0, stream>>>(Op, mlb, Ah);
    gemm_f16_m64_k<<<dim3(64, 8), 256, 0, stream>>>(Ah, wprojT, out, b_proj, 4096, 1024, 1024);
}